// Round 1
// baseline (97.937 us; speedup 1.0000x reference)
//
#include <hip/hip_runtime.h>
#include <hip/hip_bf16.h>

// ---------------------------------------------------------------------------
// Kernel 1: build M = Re(U^T_conj Z0 U) for the batch-uniform variational
// circuit. Runs on a single thread (trivial work, once per launch).
// State index k = q0*4 + q1*2 + q2 (matches [B,2,2,2] reference layout).
// ---------------------------------------------------------------------------
__global__ void vqc_build_M(const float* __restrict__ w, float* __restrict__ M) {
    if (threadIdx.x != 0 || blockIdx.x != 0) return;

    float Ur[8][8], Ui[8][8];   // U[k][j] = (U e_j)_k

    for (int j = 0; j < 8; ++j) {
        float ar[8], ai[8];
        for (int k = 0; k < 8; ++k) { ar[k] = 0.f; ai[k] = 0.f; }
        ar[j] = 1.0f;

        for (int l = 0; l < 3; ++l) {
            for (int i = 0; i < 3; ++i) {
                const float th = w[(l * 3 + i) * 2 + 0];
                const float ph = w[(l * 3 + i) * 2 + 1];
                const int   m  = 1 << (2 - i);          // bit mask of qubit i

                // RY(th) on qubit i
                const float c = cosf(0.5f * th), s = sinf(0.5f * th);
                for (int k = 0; k < 8; ++k) {
                    if (k & m) continue;
                    const float a0r = ar[k],     a0i = ai[k];
                    const float a1r = ar[k | m], a1i = ai[k | m];
                    ar[k]     = c * a0r - s * a1r;  ai[k]     = c * a0i - s * a1i;
                    ar[k | m] = s * a0r + c * a1r;  ai[k | m] = s * a0i + c * a1i;
                }

                // RZ(ph) on qubit i: bit0 -> e^{-i ph/2}, bit1 -> e^{+i ph/2}
                const float cz = cosf(0.5f * ph), sz = sinf(0.5f * ph);
                for (int k = 0; k < 8; ++k) {
                    const float pr = cz;
                    const float pi = (k & m) ? sz : -sz;
                    const float r  = ar[k] * pr - ai[k] * pi;
                    const float q  = ar[k] * pi + ai[k] * pr;
                    ar[k] = r; ai[k] = q;
                }
            }
            // CNOT(0,1): control q0 (mask 4), target q1 (mask 2) -> swap 4<->6, 5<->7
            for (int k = 4; k <= 5; ++k) {
                const int k2 = k | 2;
                float tr = ar[k]; ar[k] = ar[k2]; ar[k2] = tr;
                float ti = ai[k]; ai[k] = ai[k2]; ai[k2] = ti;
            }
            // CNOT(1,2): control q1 (mask 2), target q2 (mask 1) -> swap 2<->3, 6<->7
            for (int k = 2; k <= 6; k += 4) {
                const int k2 = k | 1;
                float tr = ar[k]; ar[k] = ar[k2]; ar[k2] = tr;
                float ti = ai[k]; ai[k] = ai[k2]; ai[k2] = ti;
            }
        }

        for (int k = 0; k < 8; ++k) { Ur[k][j] = ar[k]; Ui[k][j] = ai[k]; }
    }

    // M[a][b] = sum_k z(k) * (Ur[k][a]*Ur[k][b] + Ui[k][a]*Ui[k][b]),
    // z(k) = +1 if qubit0 bit (k>>2) is 0, else -1.
    for (int a = 0; a < 8; ++a) {
        for (int b = 0; b < 8; ++b) {
            float acc = 0.f;
            for (int k = 0; k < 8; ++k) {
                const float z = (k < 4) ? 1.f : -1.f;
                acc += z * (Ur[k][a] * Ur[k][b] + Ui[k][a] * Ui[k][b]);
            }
            M[a * 8 + b] = acc;
        }
    }
}

// ---------------------------------------------------------------------------
// Kernel 2: per batch element, build the real separable encoded state and
// evaluate the quadratic form psi^T M psi.  Memory-bound: 16 B load + 4 B
// store per thread.
// ---------------------------------------------------------------------------
__global__ __launch_bounds__(256) void vqc_eval(const float* __restrict__ x,
                                                const float* __restrict__ M,
                                                float* __restrict__ out,
                                                int B) {
    const int b = blockIdx.x * blockDim.x + threadIdx.x;
    if (b >= B) return;

    // x row is 32 B; float4 load of the first 16 B (x0..x3, we need x0..x2).
    const float4 xv = *reinterpret_cast<const float4*>(x + (size_t)b * 8);

    float s0, c0, s1, c1, s2, c2;
    __sincosf(0.5f * xv.x, &s0, &c0);
    __sincosf(0.5f * xv.y, &s1, &c1);
    __sincosf(0.5f * xv.z, &s2, &c2);

    const float t0[2] = {c0, s0};
    const float t1[2] = {c1, s1};
    const float t2[2] = {c2, s2};

    float psi[8];
#pragma unroll
    for (int k = 0; k < 8; ++k)
        psi[k] = t0[(k >> 2) & 1] * t1[(k >> 1) & 1] * t2[k & 1];

    float acc = 0.f;
#pragma unroll
    for (int i = 0; i < 8; ++i) {
        float r = 0.f;
#pragma unroll
        for (int j = 0; j < 8; ++j)
            r = fmaf(M[i * 8 + j], psi[j], r);
        acc = fmaf(psi[i], r, acc);
    }

    out[b] = acc;
}

// ---------------------------------------------------------------------------
extern "C" void kernel_launch(void* const* d_in, const int* in_sizes, int n_in,
                              void* d_out, int out_size, void* d_ws, size_t ws_size,
                              hipStream_t stream) {
    const float* x = (const float*)d_in[0];   // [B, 8] f32
    const float* w = (const float*)d_in[1];   // [3, 3, 2] f32
    float* out = (float*)d_out;               // [B, 1] f32
    float* M   = (float*)d_ws;                // 64 floats scratch

    const int B = out_size;                   // 524288

    vqc_build_M<<<1, 64, 0, stream>>>(w, M);
    vqc_eval<<<(B + 255) / 256, 256, 0, stream>>>(x, M, out, B);
}

// Round 2
// 15.408 us; speedup vs baseline: 6.3562x; 6.3562x over previous
//
#include <hip/hip_runtime.h>
#include <hip/hip_bf16.h>

// ---------------------------------------------------------------------------
// Kernel 1: build M = Re(U^dag Z0 U) for the batch-uniform variational
// circuit, parallelized: lane j < 8 propagates column j of U (8 complex
// amps in registers, all loops fully unrolled -> static indices), U goes to
// LDS, then lane = a*8+b computes M[a][b].
// State index k = q0*4 + q1*2 + q2 (matches [B,2,2,2] reference layout).
// ---------------------------------------------------------------------------
__global__ __launch_bounds__(64) void vqc_build_M(const float* __restrict__ w,
                                                  float* __restrict__ M) {
    __shared__ float sUr[8][8], sUi[8][8];   // [k][column]
    const int lane = threadIdx.x;

    if (lane < 8) {
        // 18 angles: 9 (RY, RZ) pairs; all active lanes compute all sincos
        // (uniform scalar loads, cheap vector transcendentals).
        float ryc[9], rys[9], rzc[9], rzs[9];
#pragma unroll
        for (int g = 0; g < 9; ++g) {
            __sincosf(0.5f * w[2 * g + 0], &rys[g], &ryc[g]);
            __sincosf(0.5f * w[2 * g + 1], &rzs[g], &rzc[g]);
        }

        float ar[8], ai[8];
#pragma unroll
        for (int k = 0; k < 8; ++k) {
            ar[k] = (k == lane) ? 1.0f : 0.0f;
            ai[k] = 0.0f;
        }

#pragma unroll
        for (int l = 0; l < 3; ++l) {
#pragma unroll
            for (int i = 0; i < 3; ++i) {
                const int g = l * 3 + i;
                const int m = 1 << (2 - i);          // bit mask of qubit i

                // RY on qubit i
                const float c = ryc[g], s = rys[g];
#pragma unroll
                for (int k = 0; k < 8; ++k) {
                    if (k & m) continue;
                    const float a0r = ar[k],     a0i = ai[k];
                    const float a1r = ar[k | m], a1i = ai[k | m];
                    ar[k]     = c * a0r - s * a1r;  ai[k]     = c * a0i - s * a1i;
                    ar[k | m] = s * a0r + c * a1r;  ai[k | m] = s * a0i + c * a1i;
                }

                // RZ on qubit i: bit0 -> e^{-i ph/2}, bit1 -> e^{+i ph/2}
                const float cz = rzc[g], sz = rzs[g];
#pragma unroll
                for (int k = 0; k < 8; ++k) {
                    const float pi = (k & m) ? sz : -sz;
                    const float r  = ar[k] * cz - ai[k] * pi;
                    const float q  = ar[k] * pi + ai[k] * cz;
                    ar[k] = r; ai[k] = q;
                }
            }
            // CNOT(0,1): swap 4<->6, 5<->7
#pragma unroll
            for (int k = 4; k <= 5; ++k) {
                const int k2 = k | 2;
                float tr = ar[k]; ar[k] = ar[k2]; ar[k2] = tr;
                float ti = ai[k]; ai[k] = ai[k2]; ai[k2] = ti;
            }
            // CNOT(1,2): swap 2<->3, 6<->7
#pragma unroll
            for (int k = 2; k <= 6; k += 4) {
                const int k2 = k | 1;
                float tr = ar[k]; ar[k] = ar[k2]; ar[k2] = tr;
                float ti = ai[k]; ai[k] = ai[k2]; ai[k2] = ti;
            }
        }

#pragma unroll
        for (int k = 0; k < 8; ++k) { sUr[k][lane] = ar[k]; sUi[k][lane] = ai[k]; }
    }
    __syncthreads();

    // M[a][b] = sum_k z(k) * (Ur[k][a]*Ur[k][b] + Ui[k][a]*Ui[k][b])
    const int a = lane >> 3, b = lane & 7;
    float acc = 0.f;
#pragma unroll
    for (int k = 0; k < 8; ++k) {
        const float z = (k < 4) ? 1.f : -1.f;
        acc += z * (sUr[k][a] * sUr[k][b] + sUi[k][a] * sUi[k][b]);
    }
    M[lane] = acc;
}

// ---------------------------------------------------------------------------
// Kernel 2: per batch element, build the real separable encoded state and
// evaluate the quadratic form psi^T M psi.  Memory-bound: 16 B load + 4 B
// store per thread.
// ---------------------------------------------------------------------------
__global__ __launch_bounds__(256) void vqc_eval(const float* __restrict__ x,
                                                const float* __restrict__ M,
                                                float* __restrict__ out,
                                                int B) {
    const int b = blockIdx.x * blockDim.x + threadIdx.x;
    if (b >= B) return;

    // x row is 32 B; float4 load of the first 16 B (x0..x3, we need x0..x2).
    const float4 xv = *reinterpret_cast<const float4*>(x + (size_t)b * 8);

    float s0, c0, s1, c1, s2, c2;
    __sincosf(0.5f * xv.x, &s0, &c0);
    __sincosf(0.5f * xv.y, &s1, &c1);
    __sincosf(0.5f * xv.z, &s2, &c2);

    const float t0[2] = {c0, s0};
    const float t1[2] = {c1, s1};
    const float t2[2] = {c2, s2};

    float psi[8];
#pragma unroll
    for (int k = 0; k < 8; ++k)
        psi[k] = t0[(k >> 2) & 1] * t1[(k >> 1) & 1] * t2[k & 1];

    float acc = 0.f;
#pragma unroll
    for (int i = 0; i < 8; ++i) {
        float r = 0.f;
#pragma unroll
        for (int j = 0; j < 8; ++j)
            r = fmaf(M[i * 8 + j], psi[j], r);
        acc = fmaf(psi[i], r, acc);
    }

    out[b] = acc;
}

// ---------------------------------------------------------------------------
extern "C" void kernel_launch(void* const* d_in, const int* in_sizes, int n_in,
                              void* d_out, int out_size, void* d_ws, size_t ws_size,
                              hipStream_t stream) {
    const float* x = (const float*)d_in[0];   // [B, 8] f32
    const float* w = (const float*)d_in[1];   // [3, 3, 2] f32
    float* out = (float*)d_out;               // [B, 1] f32
    float* M   = (float*)d_ws;                // 64 floats scratch

    const int B = out_size;                   // 524288

    vqc_build_M<<<1, 64, 0, stream>>>(w, M);
    vqc_eval<<<(B + 255) / 256, 256, 0, stream>>>(x, M, out, B);
}

// Round 3
// 11.060 us; speedup vs baseline: 8.8549x; 1.3931x over previous
//
#include <hip/hip_runtime.h>
#include <hip/hip_bf16.h>

// ---------------------------------------------------------------------------
// Fully fused VQC kernel.
//
// Math: the data-dependent part of the circuit is only the 3 encoding RY
// gates on |000>, giving a REAL separable state
//   psi_k = t0[k>>2] * t1[(k>>1)&1] * t2[k&1],  t(0,x)=cos(x/2), t(1,x)=sin(x/2).
// Everything after (9 RY + 9 RZ + 6 CNOT, batch-uniform weights) is one 8x8
// unitary U, and  out = psi^T M psi  with  M = Re(U^dag Z0 U)  (real symmetric,
// since psi is real).
//
// Each block builds M in LDS (lanes 0-7 of wave 0 each propagate one column
// of U through the fully-unrolled 18-gate chain; then 64 lanes form M), then
// all 256 threads stream batch elements: one float4 load, 3 sincos, 84 FMAs,
// one float store.  Memory-bound: 32 B/row fetched (64 B-line granularity),
// 4 B stored.
// ---------------------------------------------------------------------------
__global__ __launch_bounds__(256) void vqc_fused(const float* __restrict__ x,
                                                 const float* __restrict__ w,
                                                 float* __restrict__ out,
                                                 int B) {
    __shared__ float sUr[8][8], sUi[8][8];  // [k][column]
    __shared__ float sM[64];

    const int tid = threadIdx.x;

    // ---- per-block M build (redundant across blocks, overlapped) ----------
    if (tid < 8) {
        float ar[8], ai[8];
#pragma unroll
        for (int k = 0; k < 8; ++k) {
            ar[k] = (k == tid) ? 1.0f : 0.0f;
            ai[k] = 0.0f;
        }

#pragma unroll
        for (int l = 0; l < 3; ++l) {
#pragma unroll
            for (int i = 0; i < 3; ++i) {
                const int g = l * 3 + i;
                const int m = 1 << (2 - i);          // bit mask of qubit i

                // RY(w[g][0]) on qubit i
                float s, c;
                __sincosf(0.5f * w[2 * g + 0], &s, &c);
#pragma unroll
                for (int k = 0; k < 8; ++k) {
                    if (k & m) continue;
                    const float a0r = ar[k],     a0i = ai[k];
                    const float a1r = ar[k | m], a1i = ai[k | m];
                    ar[k]     = c * a0r - s * a1r;  ai[k]     = c * a0i - s * a1i;
                    ar[k | m] = s * a0r + c * a1r;  ai[k | m] = s * a0i + c * a1i;
                }

                // RZ(w[g][1]) on qubit i: bit0 -> e^{-i p/2}, bit1 -> e^{+i p/2}
                float sz, cz;
                __sincosf(0.5f * w[2 * g + 1], &sz, &cz);
#pragma unroll
                for (int k = 0; k < 8; ++k) {
                    const float pi = (k & m) ? sz : -sz;
                    const float r  = ar[k] * cz - ai[k] * pi;
                    const float q  = ar[k] * pi + ai[k] * cz;
                    ar[k] = r; ai[k] = q;
                }
            }
            // CNOT(0,1): swap 4<->6, 5<->7
#pragma unroll
            for (int k = 4; k <= 5; ++k) {
                const int k2 = k | 2;
                float tr = ar[k]; ar[k] = ar[k2]; ar[k2] = tr;
                float ti = ai[k]; ai[k] = ai[k2]; ai[k2] = ti;
            }
            // CNOT(1,2): swap 2<->3, 6<->7
#pragma unroll
            for (int k = 2; k <= 6; k += 4) {
                const int k2 = k | 1;
                float tr = ar[k]; ar[k] = ar[k2]; ar[k2] = tr;
                float ti = ai[k]; ai[k] = ai[k2]; ai[k2] = ti;
            }
        }

#pragma unroll
        for (int k = 0; k < 8; ++k) { sUr[k][tid] = ar[k]; sUi[k][tid] = ai[k]; }
    }
    __syncthreads();

    if (tid < 64) {
        // M[a][b] = sum_k z(k) * (Ur[k][a]*Ur[k][b] + Ui[k][a]*Ui[k][b])
        const int a = tid >> 3, b = tid & 7;
        float acc = 0.f;
#pragma unroll
        for (int k = 0; k < 8; ++k) {
            const float z = (k < 4) ? 1.f : -1.f;
            acc += z * (sUr[k][a] * sUr[k][b] + sUi[k][a] * sUi[k][b]);
        }
        sM[tid] = acc;
    }
    __syncthreads();

    // ---- streaming phase --------------------------------------------------
    const int b = blockIdx.x * blockDim.x + tid;
    if (b >= B) return;

    const float4 xv = *reinterpret_cast<const float4*>(x + (size_t)b * 8);

    float s0, c0, s1, c1, s2, c2;
    __sincosf(0.5f * xv.x, &s0, &c0);
    __sincosf(0.5f * xv.y, &s1, &c1);
    __sincosf(0.5f * xv.z, &s2, &c2);

    const float t0[2] = {c0, s0};
    const float t1[2] = {c1, s1};
    const float t2[2] = {c2, s2};

    float psi[8];
#pragma unroll
    for (int k = 0; k < 8; ++k)
        psi[k] = t0[(k >> 2) & 1] * t1[(k >> 1) & 1] * t2[k & 1];

    float acc = 0.f;
#pragma unroll
    for (int i = 0; i < 8; ++i) {
        float r = 0.f;
#pragma unroll
        for (int j = 0; j < 8; ++j)
            r = fmaf(sM[i * 8 + j], psi[j], r);
        acc = fmaf(psi[i], r, acc);
    }

    out[b] = acc;
}

// ---------------------------------------------------------------------------
extern "C" void kernel_launch(void* const* d_in, const int* in_sizes, int n_in,
                              void* d_out, int out_size, void* d_ws, size_t ws_size,
                              hipStream_t stream) {
    const float* x = (const float*)d_in[0];   // [B, 8] f32
    const float* w = (const float*)d_in[1];   // [3, 3, 2] f32
    float* out = (float*)d_out;               // [B, 1] f32

    const int B = out_size;                   // 524288

    vqc_fused<<<(B + 255) / 256, 256, 0, stream>>>(x, w, out, B);
}

// Round 4
// 10.346 us; speedup vs baseline: 9.4659x; 1.0690x over previous
//
#include <hip/hip_runtime.h>
#include <hip/hip_bf16.h>

// ---------------------------------------------------------------------------
// Fully fused VQC kernel, v2.
//
// out = psi^T M psi,  psi = separable real encoded state (3 angles from x),
// M = Re(U^dag Z0 U) with U the batch-uniform variational 8x8 unitary.
//
// v2 changes vs v1:
//  - M broadcast moved off the LDS pipe: each lane reads sM[lane] once, the
//    72-FMA quadratic form pulls m_ij via v_readlane (SGPR scalar operand of
//    v_fma_f32).  v1 did 64 ds_read_b32 per THREAD -> ~10k LDS-port cycles
//    per CU; v2 does 1 per thread.
//  - 2 batch elements per thread (readlanes amortized, float2 coalesced
//    store, half as many redundant per-block M builds).
// ---------------------------------------------------------------------------
__global__ __launch_bounds__(256) void vqc_fused(const float* __restrict__ x,
                                                 const float* __restrict__ w,
                                                 float* __restrict__ out,
                                                 int B2 /* = B/2 */) {
    __shared__ float sUr[8][8], sUi[8][8];  // [k][column]
    __shared__ float sM[64];

    const int tid = threadIdx.x;

    // ---- per-block M build (wave 0 only; redundant across blocks) ---------
    if (tid < 8) {
        float ar[8], ai[8];
#pragma unroll
        for (int k = 0; k < 8; ++k) {
            ar[k] = (k == tid) ? 1.0f : 0.0f;
            ai[k] = 0.0f;
        }

#pragma unroll
        for (int l = 0; l < 3; ++l) {
#pragma unroll
            for (int i = 0; i < 3; ++i) {
                const int g = l * 3 + i;
                const int m = 1 << (2 - i);          // bit mask of qubit i

                float s, c;
                __sincosf(0.5f * w[2 * g + 0], &s, &c);
#pragma unroll
                for (int k = 0; k < 8; ++k) {
                    if (k & m) continue;
                    const float a0r = ar[k],     a0i = ai[k];
                    const float a1r = ar[k | m], a1i = ai[k | m];
                    ar[k]     = c * a0r - s * a1r;  ai[k]     = c * a0i - s * a1i;
                    ar[k | m] = s * a0r + c * a1r;  ai[k | m] = s * a0i + c * a1i;
                }

                float sz, cz;
                __sincosf(0.5f * w[2 * g + 1], &sz, &cz);
#pragma unroll
                for (int k = 0; k < 8; ++k) {
                    const float pi = (k & m) ? sz : -sz;
                    const float r  = ar[k] * cz - ai[k] * pi;
                    const float q  = ar[k] * pi + ai[k] * cz;
                    ar[k] = r; ai[k] = q;
                }
            }
            // CNOT(0,1): swap 4<->6, 5<->7
#pragma unroll
            for (int k = 4; k <= 5; ++k) {
                const int k2 = k | 2;
                float tr = ar[k]; ar[k] = ar[k2]; ar[k2] = tr;
                float ti = ai[k]; ai[k] = ai[k2]; ai[k2] = ti;
            }
            // CNOT(1,2): swap 2<->3, 6<->7
#pragma unroll
            for (int k = 2; k <= 6; k += 4) {
                const int k2 = k | 1;
                float tr = ar[k]; ar[k] = ar[k2]; ar[k2] = tr;
                float ti = ai[k]; ai[k] = ai[k2]; ai[k2] = ti;
            }
        }

#pragma unroll
        for (int k = 0; k < 8; ++k) { sUr[k][tid] = ar[k]; sUi[k][tid] = ai[k]; }
    }
    __syncthreads();

    if (tid < 64) {
        const int a = tid >> 3, b = tid & 7;
        float acc = 0.f;
#pragma unroll
        for (int k = 0; k < 8; ++k) {
            const float z = (k < 4) ? 1.f : -1.f;
            acc += z * (sUr[k][a] * sUr[k][b] + sUi[k][a] * sUi[k][b]);
        }
        sM[tid] = acc;
    }
    __syncthreads();

    // Each lane holds one M element; m_ij comes from v_readlane (SGPR).
    const float mv = sM[tid & 63];

    // ---- streaming phase: 2 elements per thread ---------------------------
    const int t = blockIdx.x * blockDim.x + tid;   // t in [0, B/2)
    if (t >= B2) return;

    const float4 xa = *reinterpret_cast<const float4*>(x + (size_t)t * 16);      // row 2t
    const float4 xb = *reinterpret_cast<const float4*>(x + (size_t)t * 16 + 8);  // row 2t+1

    float psiA[8], psiB[8];
    {
        float s0, c0, s1, c1, s2, c2;
        __sincosf(0.5f * xa.x, &s0, &c0);
        __sincosf(0.5f * xa.y, &s1, &c1);
        __sincosf(0.5f * xa.z, &s2, &c2);
        const float t0[2] = {c0, s0}, t1[2] = {c1, s1}, t2[2] = {c2, s2};
#pragma unroll
        for (int k = 0; k < 8; ++k)
            psiA[k] = t0[(k >> 2) & 1] * t1[(k >> 1) & 1] * t2[k & 1];
    }
    {
        float s0, c0, s1, c1, s2, c2;
        __sincosf(0.5f * xb.x, &s0, &c0);
        __sincosf(0.5f * xb.y, &s1, &c1);
        __sincosf(0.5f * xb.z, &s2, &c2);
        const float t0[2] = {c0, s0}, t1[2] = {c1, s1}, t2[2] = {c2, s2};
#pragma unroll
        for (int k = 0; k < 8; ++k)
            psiB[k] = t0[(k >> 2) & 1] * t1[(k >> 1) & 1] * t2[k & 1];
    }

    float accA = 0.f, accB = 0.f;
#pragma unroll
    for (int i = 0; i < 8; ++i) {
        float rA = 0.f, rB = 0.f;
#pragma unroll
        for (int j = 0; j < 8; ++j) {
            const float mij = __int_as_float(
                __builtin_amdgcn_readlane(__float_as_int(mv), i * 8 + j));
            rA = fmaf(mij, psiA[j], rA);
            rB = fmaf(mij, psiB[j], rB);
        }
        accA = fmaf(psiA[i], rA, accA);
        accB = fmaf(psiB[i], rB, accB);
    }

    *reinterpret_cast<float2*>(out + (size_t)t * 2) = make_float2(accA, accB);
}

// ---------------------------------------------------------------------------
extern "C" void kernel_launch(void* const* d_in, const int* in_sizes, int n_in,
                              void* d_out, int out_size, void* d_ws, size_t ws_size,
                              hipStream_t stream) {
    const float* x = (const float*)d_in[0];   // [B, 8] f32
    const float* w = (const float*)d_in[1];   // [3, 3, 2] f32
    float* out = (float*)d_out;               // [B, 1] f32

    const int B = out_size;                   // 524288 (divisible by 512)
    const int B2 = B / 2;

    vqc_fused<<<(B2 + 255) / 256, 256, 0, stream>>>(x, w, out, B2);
}